// Round 1
// baseline (561.970 us; speedup 1.0000x reference)
//
#include <hip/hip_runtime.h>

// Problem: x (B=8, N=8192, C=64) fp32, idx (B, N, K=16) int32.
// out[b][n][c][k]      = x[b][idx[b,n,k]][c] - x[b][n][c]   (c in [0,64))
// out[b][n][64+c][k]   = x[b][n][c]
// out shape (B, N, 2C, K) fp32, flat = point*2048 + c2*16 + k where point=b*N+n.

constexpr int N = 8192;
constexpr int C = 64;
constexpr int K = 16;
constexpr int PAD = 68;   // padded row stride: 68%32==4 -> 2 lanes/bank (free); 272B keeps float4 16B-aligned

__global__ __launch_bounds__(256) void edge_feature_kernel(
    const float* __restrict__ x,
    const int*   __restrict__ idx,
    float*       __restrict__ out) {
  const int point = blockIdx.x;          // b*N + n
  const int b     = point >> 13;         // N = 8192
  const int tid   = threadIdx.x;

  __shared__ float s_nb[K * PAD];        // neighbor rows, padded
  __shared__ float s_c[C];               // center row
  __shared__ int   s_idx[K];

  // phase 0: indices + center row
  if (tid < K) s_idx[tid] = idx[(size_t)point * K + tid];
  if (tid >= 64 && tid < 64 + C) s_c[tid - 64] = x[(size_t)point * C + (tid - 64)];
  __syncthreads();

  // phase 1: stage 16 neighbor rows (16 float4 per row, 256 threads -> 1 float4 each)
  {
    const int k  = tid >> 4;             // row
    const int c4 = tid & 15;             // float4 within row
    const size_t row_base = ((size_t)b * N + (size_t)s_idx[k]) * C;
    float4 v = reinterpret_cast<const float4*>(x + row_base)[c4];
    *reinterpret_cast<float4*>(s_nb + k * PAD + c4 * 4) = v;
  }
  __syncthreads();

  // phase 2: write 2048 floats = 512 float4, 2 per thread, fully coalesced
  float4* op4 = reinterpret_cast<float4*>(out + (size_t)point * (2 * C * K));
  #pragma unroll
  for (int i = 0; i < 2; ++i) {
    const int f     = tid + i * 256;     // float4 index in [0,512)
    const int c2    = f >> 2;            // channel (0..127), wave-uniform branch below
    const int kbase = (f & 3) * 4;       // first k of this float4
    float4 v;
    if (c2 < C) {
      const float cen = s_c[c2];
      v.x = s_nb[(kbase + 0) * PAD + c2] - cen;
      v.y = s_nb[(kbase + 1) * PAD + c2] - cen;
      v.z = s_nb[(kbase + 2) * PAD + c2] - cen;
      v.w = s_nb[(kbase + 3) * PAD + c2] - cen;
    } else {
      const float cen = s_c[c2 - C];
      v = make_float4(cen, cen, cen, cen);
    }
    op4[f] = v;
  }
}

extern "C" void kernel_launch(void* const* d_in, const int* in_sizes, int n_in,
                              void* d_out, int out_size, void* d_ws, size_t ws_size,
                              hipStream_t stream) {
  const float* x   = (const float*)d_in[0];
  const int*   idx = (const int*)d_in[1];
  float*       out = (float*)d_out;

  const int B = 8;
  const int n_points = B * N;            // 65536 blocks
  edge_feature_kernel<<<n_points, 256, 0, stream>>>(x, idx, out);
}

// Round 5
// 539.661 us; speedup vs baseline: 1.0413x; 1.0413x over previous
//
#include <hip/hip_runtime.h>

// x (B=8, N=8192, C=64) fp32, idx (B, N, K=16) int32.
// out[b][n][c][k]    = x[b][idx[b,n,k]][c] - x[b][n][c]   (c in [0,64))
// out[b][n][64+c][k] = x[b][n][c]
// out flat = point*2048 + c2*16 + k, point = b*N+n.

typedef float f32x4 __attribute__((ext_vector_type(4)));   // native vector: OK for nontemporal builtins

constexpr int NPTS = 8192;   // N
constexpr int C    = 64;
constexpr int K    = 16;
constexpr int P    = 4;      // points per block
constexpr int PAD  = 68;     // 68%32==4 -> read-phase 2 lanes/bank (free); 272B row keeps float4 aligned
constexpr int NB   = 8;      // batches

__global__ __launch_bounds__(256) void edge_feature_kernel(
    const float* __restrict__ x,
    const int*   __restrict__ idx,
    float*       __restrict__ out) {
  // Bijective XCD swizzle: nwg = 16384 = 8 * 2048. Each XCD gets a contiguous
  // 2048-block chunk = exactly one batch -> gather working set (2 MB slab)
  // is L2-resident per XCD.
  const int nwg = (NB * NPTS) / P;       // 16384
  const int cpx = nwg >> 3;              // 2048
  const int bid = blockIdx.x;
  const int swz = (bid & 7) * cpx + (bid >> 3);
  const int point0 = swz * P;            // first point (b*N + n); P | N so same batch
  const int b   = point0 >> 13;          // N = 8192
  const int tid = threadIdx.x;

  __shared__ float s_nb[P * K * PAD];    // 17408 B -> 8 blocks/CU (thread-limited)

  const int k  = tid >> 4;               // neighbor row 0..15
  const int c4 = tid & 15;               // float4 within row

  // ---- gather phase: all idx loads, then all row loads (deep MLP), then LDS
  int nk[P];
  #pragma unroll
  for (int i = 0; i < P; ++i)
    nk[i] = idx[(size_t)(point0 + i) * K + k];   // 16 lanes share each addr (broadcast)

  f32x4 v[P];
  #pragma unroll
  for (int i = 0; i < P; ++i) {
    const size_t rb = ((size_t)b * NPTS + (size_t)nk[i]) * C;
    v[i] = reinterpret_cast<const f32x4*>(x + rb)[c4];
  }

  #pragma unroll
  for (int i = 0; i < P; ++i)
    *reinterpret_cast<f32x4*>(s_nb + (i * K + k) * PAD + c4 * 4) = v[i];

  __syncthreads();   // the only barrier

  // ---- write phase: P*512 float4 = 8 per thread, fully coalesced, nontemporal
  f32x4* op4 = reinterpret_cast<f32x4*>(out) + (size_t)point0 * (2 * C * K / 4);
  #pragma unroll
  for (int i = 0; i < 2 * P; ++i) {
    const int f  = i * 256 + tid;        // float4 index 0..2047
    const int p  = f >> 9;               // point within block (512 float4/point)
    const int fi = f & 511;
    const int c2 = fi >> 2;              // channel 0..127 (wave-uniform branch)
    const int kb = (fi & 3) * 4;         // first k of this float4
    f32x4 w;
    if (c2 < C) {
      const float cen = x[(size_t)(point0 + p) * C + c2];   // L1-broadcast
      const float* sp = s_nb + (p * K + kb) * PAD + c2;
      w.x = sp[0 * PAD] - cen;
      w.y = sp[1 * PAD] - cen;
      w.z = sp[2 * PAD] - cen;
      w.w = sp[3 * PAD] - cen;
    } else {
      const float cen = x[(size_t)(point0 + p) * C + (c2 - C)];
      w = (f32x4){cen, cen, cen, cen};
    }
    __builtin_nontemporal_store(w, op4 + f);
  }
}

extern "C" void kernel_launch(void* const* d_in, const int* in_sizes, int n_in,
                              void* d_out, int out_size, void* d_ws, size_t ws_size,
                              hipStream_t stream) {
  const float* x   = (const float*)d_in[0];
  const int*   idx = (const int*)d_in[1];
  float*       out = (float*)d_out;

  const int n_blocks = (NB * NPTS) / P;  // 16384
  edge_feature_kernel<<<n_blocks, 256, 0, stream>>>(x, idx, out);
}